// Round 3
// baseline (308.519 us; speedup 1.0000x reference)
//
#include <hip/hip_runtime.h>
#include <math.h>

#define IN_CH 128
#define G4    512   // 4*IN
#define K1    256   // 2*IN
#define SPLIT 8     // blocks per segment in attention

__device__ __forceinline__ float sigmoidf_(float v){ return 1.f/(1.f + expf(-v)); }

// Transpose w_ih [512,256] -> wTih [256,512]; w_hh [512,128] -> wThh [128,512]
__global__ void transpose_w_kernel(const float* __restrict__ w_ih, const float* __restrict__ w_hh,
                                   float* __restrict__ wTih, float* __restrict__ wThh){
  int idx = blockIdx.x*blockDim.x + threadIdx.x;
  if (idx < G4*K1){ int g = idx / K1; int k = idx - g*K1; wTih[k*G4 + g] = w_ih[idx]; }
  if (idx < G4*IN_CH){ int g = idx / IN_CH; int k = idx - g*IN_CH; wThh[k*G4 + g] = w_hh[idx]; }
}

// segs[b] = lower_bound(batch, b); segs[B] = N   (batch is sorted)
__global__ void seg_bounds_kernel(const int* __restrict__ batch, int N, int B, int* __restrict__ segs){
  int b = blockIdx.x*blockDim.x + threadIdx.x;
  if (b > B) return;
  if (b == B){ segs[B] = N; return; }
  int lo = 0, hi = N;
  while (lo < hi){ int mid = (lo + hi) >> 1; if (batch[mid] < b) lo = mid + 1; else hi = mid; }
  segs[b] = lo;
}

// gates[b,g] = qstar[b,:] . wTih[:,g] + h[b,:] . wThh[:,g] + b_ih[g] + b_hh[g]
__global__ __launch_bounds__(256) void lstm_gemv_kernel(
    const float* __restrict__ qstar, const float* __restrict__ h,
    const float* __restrict__ wTih, const float* __restrict__ wThh,
    const float* __restrict__ b_ih, const float* __restrict__ b_hh,
    float* __restrict__ gates){
  int g    = blockIdx.y*256 + threadIdx.x;
  int row0 = blockIdx.x*8;
  __shared__ float qs[8][K1];
  __shared__ float hs[8][IN_CH];
  for (int t = threadIdx.x; t < 8*K1; t += 256){ int r = t >> 8; int k = t & 255; qs[r][k] = qstar[(row0+r)*K1 + k]; }
  for (int t = threadIdx.x; t < 8*IN_CH; t += 256){ int r = t >> 7; int k = t & 127; hs[r][k] = h[(row0+r)*IN_CH + k]; }
  __syncthreads();
  float bias = b_ih[g] + b_hh[g];
  float acc[8];
#pragma unroll
  for (int r = 0; r < 8; ++r) acc[r] = bias;
  for (int k4 = 0; k4 < K1/4; ++k4){
    float w0 = wTih[(4*k4+0)*G4 + g];
    float w1 = wTih[(4*k4+1)*G4 + g];
    float w2 = wTih[(4*k4+2)*G4 + g];
    float w3 = wTih[(4*k4+3)*G4 + g];
#pragma unroll
    for (int r = 0; r < 8; ++r){
      float4 q = *reinterpret_cast<const float4*>(&qs[r][4*k4]);
      acc[r] += q.x*w0 + q.y*w1 + q.z*w2 + q.w*w3;
    }
  }
  for (int k4 = 0; k4 < IN_CH/4; ++k4){
    float w0 = wThh[(4*k4+0)*G4 + g];
    float w1 = wThh[(4*k4+1)*G4 + g];
    float w2 = wThh[(4*k4+2)*G4 + g];
    float w3 = wThh[(4*k4+3)*G4 + g];
#pragma unroll
    for (int r = 0; r < 8; ++r){
      float4 hv = *reinterpret_cast<const float4*>(&hs[r][4*k4]);
      acc[r] += hv.x*w0 + hv.y*w1 + hv.z*w2 + hv.w*w3;
    }
  }
#pragma unroll
  for (int r = 0; r < 8; ++r) gates[(row0+r)*G4 + g] = acc[r];
}

// LSTM cell update; also writes q-half of q_star
__global__ void lstm_update_kernel(const float* __restrict__ gates,
                                   float* __restrict__ h, float* __restrict__ c,
                                   float* __restrict__ qstar, int B){
  int idx = blockIdx.x*blockDim.x + threadIdx.x;
  if (idx >= B*IN_CH) return;
  int b = idx >> 7, ch = idx & 127;
  const float* gr = gates + b*G4;
  float iv = sigmoidf_(gr[ch]);
  float fv = sigmoidf_(gr[IN_CH + ch]);
  float gv = tanhf(gr[2*IN_CH + ch]);
  float ov = sigmoidf_(gr[3*IN_CH + ch]);
  float cv = fv*c[idx] + iv*gv;
  float hv = ov*tanhf(cv);
  c[idx] = cv; h[idx] = hv;
  qstar[b*K1 + ch] = hv;
}

// Single-pass online-softmax weighted readout, SPLIT blocks per segment,
// 2 waves/block, 4 rows per half-wave per iteration (deep load ILP),
// deferred-max rescale (rescale only when the running max grows).
__global__ __launch_bounds__(128) void attn_part_kernel(const float* __restrict__ x,
    const float* __restrict__ qstar, const int* __restrict__ segs,
    float* __restrict__ pm, float* __restrict__ pd, float* __restrict__ pr){
  int b = blockIdx.x, p = blockIdx.y;
  int s = segs[b], t = segs[b+1];
  int len = t - s;
  int cs = s + (int)(((long long)len * p) / SPLIT);
  int ce = s + (int)(((long long)len * (p+1)) / SPLIT);
  int tid = threadIdx.x;
  int wave = tid >> 6, lane = tid & 63;
  int half = lane >> 5, lane31 = lane & 31;
  const float4* x4 = reinterpret_cast<const float4*>(x);
  float4 qv = *reinterpret_cast<const float4*>(&qstar[b*K1 + lane31*4]);

  float m = -INFINITY, d = 0.f;
  float rx = 0.f, ry = 0.f, rz = 0.f, rw = 0.f;
  const float4 z4 = make_float4(0.f,0.f,0.f,0.f);

  // stream = (wave*2 + half); 4 streams/block, 4 consecutive rows each, stride 16
  for (int j0 = cs + (wave*2 + half)*4; j0 < ce; j0 += 16){
    bool v1 = (j0+1 < ce), v2 = (j0+2 < ce), v3 = (j0+3 < ce);
    float4 x0 = x4[(size_t)j0*(IN_CH/4) + lane31];
    float4 x1 = v1 ? x4[(size_t)(j0+1)*(IN_CH/4) + lane31] : z4;
    float4 x2 = v2 ? x4[(size_t)(j0+2)*(IN_CH/4) + lane31] : z4;
    float4 x3 = v3 ? x4[(size_t)(j0+3)*(IN_CH/4) + lane31] : z4;
    float e0 = x0.x*qv.x + x0.y*qv.y + x0.z*qv.z + x0.w*qv.w;
    float e1 = x1.x*qv.x + x1.y*qv.y + x1.z*qv.z + x1.w*qv.w;
    float e2 = x2.x*qv.x + x2.y*qv.y + x2.z*qv.z + x2.w*qv.w;
    float e3 = x3.x*qv.x + x3.y*qv.y + x3.z*qv.z + x3.w*qv.w;
#pragma unroll
    for (int off = 1; off <= 16; off <<= 1){
      e0 += __shfl_xor(e0, off);
      e1 += __shfl_xor(e1, off);
      e2 += __shfl_xor(e2, off);
      e3 += __shfl_xor(e3, off);
    }
    e1 = v1 ? e1 : -INFINITY;
    e2 = v2 ? e2 : -INFINITY;
    e3 = v3 ? e3 : -INFINITY;
    float em = fmaxf(fmaxf(e0, e1), fmaxf(e2, e3));
    if (em > m){                       // uniform per half-wave; taken ~1-2x per stream
      float corr = __expf(m - em);     // m=-inf first time -> corr=0 zeroes state
      d *= corr; rx *= corr; ry *= corr; rz *= corr; rw *= corr;
      m = em;
    }
    // m is finite here (e0 always valid), so e=-inf rows give exp()=0 safely
    float p0 = __expf(e0 - m);
    float p1 = __expf(e1 - m);
    float p2 = __expf(e2 - m);
    float p3 = __expf(e3 - m);
    d += (p0 + p1) + (p2 + p3);
    rx += p0*x0.x + p1*x1.x + p2*x2.x + p3*x3.x;
    ry += p0*x0.y + p1*x1.y + p2*x2.y + p3*x3.y;
    rz += p0*x0.z + p1*x1.z + p2*x2.z + p3*x3.z;
    rw += p0*x0.w + p1*x1.w + p2*x2.w + p3*x3.w;
  }
  // merge the two halves of each wave (same channels, xor 32)
  {
    float mo = __shfl_xor(m, 32);
    float dd = __shfl_xor(d, 32);
    float ox = __shfl_xor(rx, 32), oy = __shfl_xor(ry, 32);
    float oz = __shfl_xor(rz, 32), ow = __shfl_xor(rw, 32);
    float mn = fmaxf(m, mo);
    float c1 = (mn == -INFINITY) ? 0.f : __expf(m - mn);
    float c2 = (mn == -INFINITY) ? 0.f : __expf(mo - mn);
    d = d*c1 + dd*c2;
    rx = rx*c1 + ox*c2; ry = ry*c1 + oy*c2; rz = rz*c1 + oz*c2; rw = rw*c1 + ow*c2;
    m = mn;
  }
  __shared__ float mbuf[2], dbuf[2];
  __shared__ float rbuf[2][IN_CH];
  if (lane < 32){
    rbuf[wave][lane31*4+0] = rx; rbuf[wave][lane31*4+1] = ry;
    rbuf[wave][lane31*4+2] = rz; rbuf[wave][lane31*4+3] = rw;
  }
  if (lane == 0){ mbuf[wave] = m; dbuf[wave] = d; }
  __syncthreads();
  int part = b*SPLIT + p;
  if (tid < IN_CH){
    float M = fmaxf(mbuf[0], mbuf[1]);
    float f0 = (M == -INFINITY) ? 0.f : __expf(mbuf[0] - M);
    float f1 = (M == -INFINITY) ? 0.f : __expf(mbuf[1] - M);
    float R = rbuf[0][tid]*f0 + rbuf[1][tid]*f1;
    pr[(size_t)part*IN_CH + tid] = R;
    if (tid == 0){
      pd[part] = dbuf[0]*f0 + dbuf[1]*f1;
      pm[part] = M;
    }
  }
}

// Merge SPLIT partials per segment; write r-half of q_star
__global__ void attn_combine_kernel(const float* __restrict__ pm, const float* __restrict__ pd,
                                    const float* __restrict__ pr, float* __restrict__ qstar){
  int b = blockIdx.x; int ch = threadIdx.x;  // 128 threads
  float M = -INFINITY;
#pragma unroll
  for (int p = 0; p < SPLIT; ++p) M = fmaxf(M, pm[b*SPLIT + p]);
  float d = 0.f, r = 0.f;
#pragma unroll
  for (int p = 0; p < SPLIT; ++p){
    float mp = pm[b*SPLIT + p];
    float f = (mp == -INFINITY) ? 0.f : __expf(mp - M);
    d += pd[b*SPLIT + p] * f;
    r += pr[(size_t)(b*SPLIT + p)*IN_CH + ch] * f;
  }
  qstar[b*K1 + IN_CH + ch] = (d > 0.f) ? r/d : 0.f;
}

extern "C" void kernel_launch(void* const* d_in, const int* in_sizes, int n_in,
                              void* d_out, int out_size, void* d_ws, size_t ws_size,
                              hipStream_t stream){
  const float* x     = (const float*)d_in[0];
  const float* w_ih  = (const float*)d_in[1];
  const float* w_hh  = (const float*)d_in[2];
  const float* b_ih  = (const float*)d_in[3];
  const float* b_hh  = (const float*)d_in[4];
  const int*   batch = (const int*)d_in[5];
  int N = in_sizes[0] / IN_CH;
  int B = out_size / K1;
  float* out = (float*)d_out;   // q_star lives here

  float* ws    = (float*)d_ws;
  float* h     = ws;                    // B*128
  float* c     = h + (size_t)B*IN_CH;   // B*128
  float* wTih  = c + (size_t)B*IN_CH;   // 256*512
  float* wThh  = wTih + K1*G4;          // 128*512
  float* gates = wThh + IN_CH*G4;       // B*512
  int*   segs  = (int*)(gates + (size_t)B*G4); // B+1
  float* pm    = (float*)(segs + (B + 2));     // B*SPLIT
  float* pd    = pm + (size_t)B*SPLIT;         // B*SPLIT
  float* pr    = pd + (size_t)B*SPLIT;         // B*SPLIT*128

  hipMemsetAsync(h, 0, (size_t)B*IN_CH*2*sizeof(float), stream);
  hipMemsetAsync(d_out, 0, (size_t)out_size*sizeof(float), stream);
  transpose_w_kernel<<<(G4*K1 + 255)/256, 256, 0, stream>>>(w_ih, w_hh, wTih, wThh);
  seg_bounds_kernel<<<(B + 256)/256, 256, 0, stream>>>(batch, N, B, segs);

  for (int step = 0; step < 3; ++step){
    lstm_gemv_kernel<<<dim3(B/8, 2), 256, 0, stream>>>(out, h, wTih, wThh, b_ih, b_hh, gates);
    lstm_update_kernel<<<(B*IN_CH + 255)/256, 256, 0, stream>>>(gates, h, c, out, B);
    attn_part_kernel<<<dim3(B, SPLIT), 128, 0, stream>>>(x, out, segs, pm, pd, pr);
    attn_combine_kernel<<<B, IN_CH, 0, stream>>>(pm, pd, pr, out);
  }
}

// Round 4
// 211.240 us; speedup vs baseline: 1.4605x; 1.4605x over previous
//
#include <hip/hip_runtime.h>
#include <math.h>

#define IN_CH 128
#define G4    512   // 4*IN
#define K1    256   // 2*IN
#define SPLIT 4     // blocks per segment in attention

__device__ __forceinline__ float sigmoidf_(float v){ return 1.f/(1.f + expf(-v)); }

// All-reduce-sum over 32-lane half-wave: 4 DPP stages (VALU speed) + 1 ds_swizzle (xor16).
// After stages xor1,xor2 every 4-group is uniform, so the mirror perms are valid xor4/xor8.
__device__ __forceinline__ float allreduce32_(float v){
  int t;
  t = __builtin_amdgcn_update_dpp(0, __float_as_int(v), 0xB1, 0xF, 0xF, true);   // quad_perm [1,0,3,2] = xor1
  v += __int_as_float(t);
  t = __builtin_amdgcn_update_dpp(0, __float_as_int(v), 0x4E, 0xF, 0xF, true);   // quad_perm [2,3,0,1] = xor2
  v += __int_as_float(t);
  t = __builtin_amdgcn_update_dpp(0, __float_as_int(v), 0x141, 0xF, 0xF, true);  // row_half_mirror = xor4-equiv
  v += __int_as_float(t);
  t = __builtin_amdgcn_update_dpp(0, __float_as_int(v), 0x140, 0xF, 0xF, true);  // row_mirror = xor8-equiv
  v += __int_as_float(t);
  t = __builtin_amdgcn_ds_swizzle(__float_as_int(v), 0x401F);                    // lane ^ 16
  return v + __int_as_float(t);
}

// Transpose w_ih [512,256] -> wTih [256,512]; w_hh [512,128] -> wThh [128,512]
__global__ void transpose_w_kernel(const float* __restrict__ w_ih, const float* __restrict__ w_hh,
                                   float* __restrict__ wTih, float* __restrict__ wThh){
  int idx = blockIdx.x*blockDim.x + threadIdx.x;
  if (idx < G4*K1){ int g = idx / K1; int k = idx - g*K1; wTih[k*G4 + g] = w_ih[idx]; }
  if (idx < G4*IN_CH){ int g = idx / IN_CH; int k = idx - g*IN_CH; wThh[k*G4 + g] = w_hh[idx]; }
}

// segs[b] = lower_bound(batch, b); segs[B] = N   (batch is sorted)
__global__ void seg_bounds_kernel(const int* __restrict__ batch, int N, int B, int* __restrict__ segs){
  int b = blockIdx.x*blockDim.x + threadIdx.x;
  if (b > B) return;
  if (b == B){ segs[B] = N; return; }
  int lo = 0, hi = N;
  while (lo < hi){ int mid = (lo + hi) >> 1; if (batch[mid] < b) lo = mid + 1; else hi = mid; }
  segs[b] = lo;
}

// Step 0: q_star = h = c = 0  =>  gates = b_ih + b_hh (batch-independent).
// Compute h0/c0 from biases and broadcast into h, c, and q-half of q_star.
__global__ void lstm_init0_kernel(const float* __restrict__ b_ih, const float* __restrict__ b_hh,
                                  float* __restrict__ h, float* __restrict__ c,
                                  float* __restrict__ qstar, int B){
  int idx = blockIdx.x*blockDim.x + threadIdx.x;
  if (idx >= B*IN_CH) return;
  int b = idx >> 7, ch = idx & 127;
  float iv = sigmoidf_(b_ih[ch]          + b_hh[ch]);
  float gv = tanhf   (b_ih[2*IN_CH + ch] + b_hh[2*IN_CH + ch]);
  float ov = sigmoidf_(b_ih[3*IN_CH + ch] + b_hh[3*IN_CH + ch]);
  float cv = iv*gv;            // f*c_prev = 0
  float hv = ov*tanhf(cv);
  c[idx] = cv; h[idx] = hv;
  qstar[b*K1 + ch] = hv;
}

// Fused LSTM step (steps 1,2): gates in LDS, then cell update + q-half write.
// One block of 512 threads per 8 batch rows; thread = gate index.
__global__ __launch_bounds__(512) void lstm_fused_kernel(
    const float* __restrict__ qstar_in, float* __restrict__ h, float* __restrict__ c,
    const float* __restrict__ wTih, const float* __restrict__ wThh,
    const float* __restrict__ b_ih, const float* __restrict__ b_hh,
    float* __restrict__ qstar_out){
  int g    = threadIdx.x;      // 0..511
  int row0 = blockIdx.x*8;
  __shared__ float qs[8][K1];
  __shared__ float hs[8][IN_CH];
  __shared__ float gs[8][G4];
  for (int t = g; t < 8*K1; t += 512){ int r = t >> 8; int k = t & 255; qs[r][k] = qstar_in[(row0+r)*K1 + k]; }
  for (int t = g; t < 8*IN_CH; t += 512){ int r = t >> 7; int k = t & 127; hs[r][k] = h[(row0+r)*IN_CH + k]; }
  __syncthreads();
  float bias = b_ih[g] + b_hh[g];
  float acc[8];
#pragma unroll
  for (int r = 0; r < 8; ++r) acc[r] = bias;
  for (int k4 = 0; k4 < K1/4; ++k4){
    float w0 = wTih[(4*k4+0)*G4 + g];
    float w1 = wTih[(4*k4+1)*G4 + g];
    float w2 = wTih[(4*k4+2)*G4 + g];
    float w3 = wTih[(4*k4+3)*G4 + g];
#pragma unroll
    for (int r = 0; r < 8; ++r){
      float4 q = *reinterpret_cast<const float4*>(&qs[r][4*k4]);
      acc[r] += q.x*w0 + q.y*w1 + q.z*w2 + q.w*w3;
    }
  }
  for (int k4 = 0; k4 < IN_CH/4; ++k4){
    float w0 = wThh[(4*k4+0)*G4 + g];
    float w1 = wThh[(4*k4+1)*G4 + g];
    float w2 = wThh[(4*k4+2)*G4 + g];
    float w3 = wThh[(4*k4+3)*G4 + g];
#pragma unroll
    for (int r = 0; r < 8; ++r){
      float4 hv = *reinterpret_cast<const float4*>(&hs[r][4*k4]);
      acc[r] += hv.x*w0 + hv.y*w1 + hv.z*w2 + hv.w*w3;
    }
  }
#pragma unroll
  for (int r = 0; r < 8; ++r) gs[r][g] = acc[r];
  __syncthreads();
  for (int t = g; t < 8*IN_CH; t += 512){
    int r = t >> 7, ch = t & 127;
    int idx = (row0+r)*IN_CH + ch;
    float iv = sigmoidf_(gs[r][ch]);
    float fv = sigmoidf_(gs[r][IN_CH + ch]);
    float gv = tanhf(gs[r][2*IN_CH + ch]);
    float ov = sigmoidf_(gs[r][3*IN_CH + ch]);
    float cv = fv*c[idx] + iv*gv;
    float hv = ov*tanhf(cv);
    c[idx] = cv; h[idx] = hv;
    qstar_out[(row0+r)*K1 + ch] = hv;
  }
}

// Single-pass online-softmax weighted readout. Round-2 geometry (SPLIT=4, 256 thr),
// DPP-based 32-lane allreduce + deferred-max rescale.
__global__ __launch_bounds__(256) void attn_part_kernel(const float* __restrict__ x,
    const float* __restrict__ qstar, const int* __restrict__ segs,
    float* __restrict__ pm, float* __restrict__ pd, float* __restrict__ pr){
  int b = blockIdx.x, p = blockIdx.y;
  int s = segs[b], t = segs[b+1];
  int len = t - s;
  int cs = s + (int)(((long long)len * p) / SPLIT);
  int ce = s + (int)(((long long)len * (p+1)) / SPLIT);
  int tid = threadIdx.x;
  int wave = tid >> 6, lane = tid & 63;
  int half = lane >> 5, lane31 = lane & 31;
  const float4* x4 = reinterpret_cast<const float4*>(x);
  float4 qv = *reinterpret_cast<const float4*>(&qstar[b*K1 + lane31*4]);

  float m = -INFINITY, d = 0.f;
  float rx = 0.f, ry = 0.f, rz = 0.f, rw = 0.f;
  const float4 z4 = make_float4(0.f,0.f,0.f,0.f);

  // 8 streams/block (wave*2+half), 2 consecutive rows each, stride 16
  int stream = wave*2 + half;
  for (int j0 = cs + stream*2; j0 < ce; j0 += 16){
    int j1 = j0 + 1;
    bool v1 = (j1 < ce);
    float4 x0 = x4[(size_t)j0*(IN_CH/4) + lane31];
    float4 x1 = v1 ? x4[(size_t)j1*(IN_CH/4) + lane31] : z4;
    float e0 = x0.x*qv.x + x0.y*qv.y + x0.z*qv.z + x0.w*qv.w;
    float e1 = x1.x*qv.x + x1.y*qv.y + x1.z*qv.z + x1.w*qv.w;
    e0 = allreduce32_(e0);
    e1 = allreduce32_(e1);
    e1 = v1 ? e1 : -INFINITY;
    float em = fmaxf(e0, e1);
    if (em > m){                       // uniform per half-wave; rarely taken after warmup
      float corr = __expf(m - em);     // m=-inf first time -> corr=0 zeroes state
      d *= corr; rx *= corr; ry *= corr; rz *= corr; rw *= corr;
      m = em;
    }
    float p0 = __expf(e0 - m);
    float p1 = __expf(e1 - m);
    d += p0 + p1;
    rx += p0*x0.x + p1*x1.x;
    ry += p0*x0.y + p1*x1.y;
    rz += p0*x0.z + p1*x1.z;
    rw += p0*x0.w + p1*x1.w;
  }
  // merge the two halves of each wave (same channels, xor 32)
  {
    float mo = __shfl_xor(m, 32);
    float dd = __shfl_xor(d, 32);
    float ox = __shfl_xor(rx, 32), oy = __shfl_xor(ry, 32);
    float oz = __shfl_xor(rz, 32), ow = __shfl_xor(rw, 32);
    float mn = fmaxf(m, mo);
    float c1 = (mn == -INFINITY) ? 0.f : __expf(m - mn);
    float c2 = (mn == -INFINITY) ? 0.f : __expf(mo - mn);
    d = d*c1 + dd*c2;
    rx = rx*c1 + ox*c2; ry = ry*c1 + oy*c2; rz = rz*c1 + oz*c2; rw = rw*c1 + ow*c2;
    m = mn;
  }
  __shared__ float mbuf[4], dbuf[4];
  __shared__ float rbuf[4][IN_CH];
  if (lane < 32){
    rbuf[wave][lane31*4+0] = rx; rbuf[wave][lane31*4+1] = ry;
    rbuf[wave][lane31*4+2] = rz; rbuf[wave][lane31*4+3] = rw;
  }
  if (lane == 0){ mbuf[wave] = m; dbuf[wave] = d; }
  __syncthreads();
  int part = b*SPLIT + p;
  if (tid < IN_CH){
    float M = fmaxf(fmaxf(mbuf[0], mbuf[1]), fmaxf(mbuf[2], mbuf[3]));
    float f0 = (M == -INFINITY) ? 0.f : __expf(mbuf[0] - M);
    float f1 = (M == -INFINITY) ? 0.f : __expf(mbuf[1] - M);
    float f2 = (M == -INFINITY) ? 0.f : __expf(mbuf[2] - M);
    float f3 = (M == -INFINITY) ? 0.f : __expf(mbuf[3] - M);
    float R = rbuf[0][tid]*f0 + rbuf[1][tid]*f1 + rbuf[2][tid]*f2 + rbuf[3][tid]*f3;
    pr[(size_t)part*IN_CH + tid] = R;
    if (tid == 0){
      pd[part] = dbuf[0]*f0 + dbuf[1]*f1 + dbuf[2]*f2 + dbuf[3]*f3;
      pm[part] = M;
    }
  }
}

// Merge SPLIT partials per segment; write r-half of q_star
__global__ void attn_combine_kernel(const float* __restrict__ pm, const float* __restrict__ pd,
                                    const float* __restrict__ pr, float* __restrict__ qstar){
  int b = blockIdx.x; int ch = threadIdx.x;  // 128 threads
  float M = -INFINITY;
#pragma unroll
  for (int p = 0; p < SPLIT; ++p) M = fmaxf(M, pm[b*SPLIT + p]);
  float d = 0.f, r = 0.f;
#pragma unroll
  for (int p = 0; p < SPLIT; ++p){
    float mp = pm[b*SPLIT + p];
    float f = (mp == -INFINITY) ? 0.f : __expf(mp - M);
    d += pd[b*SPLIT + p] * f;
    r += pr[(size_t)(b*SPLIT + p)*IN_CH + ch] * f;
  }
  qstar[b*K1 + IN_CH + ch] = (d > 0.f) ? r/d : 0.f;
}

extern "C" void kernel_launch(void* const* d_in, const int* in_sizes, int n_in,
                              void* d_out, int out_size, void* d_ws, size_t ws_size,
                              hipStream_t stream){
  const float* x     = (const float*)d_in[0];
  const float* w_ih  = (const float*)d_in[1];
  const float* w_hh  = (const float*)d_in[2];
  const float* b_ih  = (const float*)d_in[3];
  const float* b_hh  = (const float*)d_in[4];
  const int*   batch = (const int*)d_in[5];
  int N = in_sizes[0] / IN_CH;
  int B = out_size / K1;
  float* out = (float*)d_out;   // q_star lives here

  float* ws    = (float*)d_ws;
  float* h     = ws;                    // B*128
  float* c     = h + (size_t)B*IN_CH;   // B*128
  float* wTih  = c + (size_t)B*IN_CH;   // 256*512
  float* wThh  = wTih + K1*G4;          // 128*512
  int*   segs  = (int*)(wThh + IN_CH*G4);      // B+1
  float* pm    = (float*)(segs + (B + 2));     // B*SPLIT
  float* pd    = pm + (size_t)B*SPLIT;         // B*SPLIT
  float* pr    = pd + (size_t)B*SPLIT;         // B*SPLIT*128

  transpose_w_kernel<<<(G4*K1 + 255)/256, 256, 0, stream>>>(w_ih, w_hh, wTih, wThh);
  seg_bounds_kernel<<<(B + 256)/256, 256, 0, stream>>>(batch, N, B, segs);
  // step 0 LSTM collapses to a bias-only broadcast (q_star, h, c all start at 0)
  lstm_init0_kernel<<<(B*IN_CH + 255)/256, 256, 0, stream>>>(b_ih, b_hh, h, c, out, B);

  for (int step = 0; step < 3; ++step){
    if (step > 0)
      lstm_fused_kernel<<<B/8, 512, 0, stream>>>(out, h, c, wTih, wThh, b_ih, b_hh, out);
    attn_part_kernel<<<dim3(B, SPLIT), 256, 0, stream>>>(x, out, segs, pm, pd, pr);
    attn_combine_kernel<<<B, IN_CH, 0, stream>>>(pm, pd, pr, out);
  }
}

// Round 5
// 202.260 us; speedup vs baseline: 1.5254x; 1.0444x over previous
//
#include <hip/hip_runtime.h>
#include <math.h>

#define IN_CH 128
#define G4    512   // 4*IN
#define K1    256   // 2*IN
#define SPLIT 4     // blocks per segment in attention

__device__ __forceinline__ float sigmoidf_(float v){ return 1.f/(1.f + expf(-v)); }

__device__ __forceinline__ float dot4_(float4 a, float4 b){
  return a.x*b.x + a.y*b.y + a.z*b.z + a.w*b.w;
}

// All-reduce-sum over each 16-lane group: 4 pure-DPP stages (VALU speed, no LDS pipe).
// After xor1,xor2 each quad is uniform, so row_half_mirror/row_mirror act as xor4/xor8.
__device__ __forceinline__ float reduce16_(float v){
  int t;
  t = __builtin_amdgcn_update_dpp(0, __float_as_int(v), 0xB1, 0xF, 0xF, true);   // quad_perm [1,0,3,2] = xor1
  v += __int_as_float(t);
  t = __builtin_amdgcn_update_dpp(0, __float_as_int(v), 0x4E, 0xF, 0xF, true);   // quad_perm [2,3,0,1] = xor2
  v += __int_as_float(t);
  t = __builtin_amdgcn_update_dpp(0, __float_as_int(v), 0x141, 0xF, 0xF, true);  // row_half_mirror = xor4
  v += __int_as_float(t);
  t = __builtin_amdgcn_update_dpp(0, __float_as_int(v), 0x140, 0xF, 0xF, true);  // row_mirror = xor8
  v += __int_as_float(t);
  return v;
}

__device__ __forceinline__ float swz16_(float v){
  return __int_as_float(__builtin_amdgcn_ds_swizzle(__float_as_int(v), 0x401F)); // lane ^ 16
}

// Prologue: transpose weights + segment bounds + step-0 LSTM collapse (bias-only).
__global__ void prologue_kernel(const float* __restrict__ w_ih, const float* __restrict__ w_hh,
                                float* __restrict__ wTih, float* __restrict__ wThh,
                                const int* __restrict__ batch, int N, int B, int* __restrict__ segs,
                                const float* __restrict__ b_ih, const float* __restrict__ b_hh,
                                float* __restrict__ h, float* __restrict__ c, float* __restrict__ qstar){
  int blk = blockIdx.x;
  if (blk < 512){                       // transpose: idx over G4*K1 = 131072
    int idx = blk*256 + threadIdx.x;
    { int g = idx / K1; int k = idx - g*K1; wTih[k*G4 + g] = w_ih[idx]; }
    if (idx < G4*IN_CH){ int g = idx / IN_CH; int k = idx - g*IN_CH; wThh[k*G4 + g] = w_hh[idx]; }
  } else if (blk < 517){                // seg bounds: b in [0, B]
    int b = (blk - 512)*256 + threadIdx.x;
    if (b > B) return;
    if (b == B){ segs[B] = N; return; }
    int lo = 0, hi = N;
    while (lo < hi){ int mid = (lo + hi) >> 1; if (batch[mid] < b) lo = mid + 1; else hi = mid; }
    segs[b] = lo;
  } else {                              // init0: idx over B*IN_CH = 131072
    int idx = (blk - 517)*256 + threadIdx.x;
    if (idx >= B*IN_CH) return;
    int b = idx >> 7, ch = idx & 127;
    float iv = sigmoidf_(b_ih[ch]           + b_hh[ch]);
    float gv = tanhf    (b_ih[2*IN_CH + ch] + b_hh[2*IN_CH + ch]);
    float ov = sigmoidf_(b_ih[3*IN_CH + ch] + b_hh[3*IN_CH + ch]);
    float cv = iv*gv;           // f*c_prev = 0
    float hv = ov*tanhf(cv);
    c[idx] = cv; h[idx] = hv;
    qstar[b*K1 + ch] = hv;
  }
}

// Fused combine(prev attn partials) + LSTM step. 8 rows/block, 512 threads.
__global__ __launch_bounds__(512) void lstm_fused_kernel(
    const float* __restrict__ qstar, const float* __restrict__ pm, const float* __restrict__ pd,
    const float* __restrict__ pr, float* __restrict__ h, float* __restrict__ c,
    const float* __restrict__ wTih, const float* __restrict__ wThh,
    const float* __restrict__ b_ih, const float* __restrict__ b_hh,
    float* __restrict__ qstar_out){
  int g    = threadIdx.x;      // 0..511
  int row0 = blockIdx.x*8;
  __shared__ float qs[8][K1];
  __shared__ float hs[8][IN_CH];
  __shared__ float gs[8][G4];
  // q-half from qstar; r-half combined from partials
  for (int t = g; t < 8*IN_CH; t += 512){ int r = t >> 7; int k = t & 127; qs[r][k] = qstar[(row0+r)*K1 + k]; }
  for (int t = g; t < 8*IN_CH; t += 512){
    int r = t >> 7, ch = t & 127; int b = row0 + r;
    float m0 = pm[b*SPLIT+0], m1 = pm[b*SPLIT+1], m2 = pm[b*SPLIT+2], m3 = pm[b*SPLIT+3];
    float M = fmaxf(fmaxf(m0, m1), fmaxf(m2, m3));
    float f0 = (M == -INFINITY) ? 0.f : __expf(m0 - M);
    float f1 = (M == -INFINITY) ? 0.f : __expf(m1 - M);
    float f2 = (M == -INFINITY) ? 0.f : __expf(m2 - M);
    float f3 = (M == -INFINITY) ? 0.f : __expf(m3 - M);
    float dd = pd[b*SPLIT+0]*f0 + pd[b*SPLIT+1]*f1 + pd[b*SPLIT+2]*f2 + pd[b*SPLIT+3]*f3;
    float rr = pr[(size_t)(b*SPLIT+0)*IN_CH + ch]*f0 + pr[(size_t)(b*SPLIT+1)*IN_CH + ch]*f1
             + pr[(size_t)(b*SPLIT+2)*IN_CH + ch]*f2 + pr[(size_t)(b*SPLIT+3)*IN_CH + ch]*f3;
    qs[r][IN_CH + ch] = (dd > 0.f) ? rr/dd : 0.f;
  }
  for (int t = g; t < 8*IN_CH; t += 512){ int r = t >> 7; int k = t & 127; hs[r][k] = h[(row0+r)*IN_CH + k]; }
  __syncthreads();
  float bias = b_ih[g] + b_hh[g];
  float acc[8];
#pragma unroll
  for (int r = 0; r < 8; ++r) acc[r] = bias;
  for (int k4 = 0; k4 < K1/4; ++k4){
    float w0 = wTih[(4*k4+0)*G4 + g];
    float w1 = wTih[(4*k4+1)*G4 + g];
    float w2 = wTih[(4*k4+2)*G4 + g];
    float w3 = wTih[(4*k4+3)*G4 + g];
#pragma unroll
    for (int r = 0; r < 8; ++r){
      float4 q = *reinterpret_cast<const float4*>(&qs[r][4*k4]);
      acc[r] += q.x*w0 + q.y*w1 + q.z*w2 + q.w*w3;
    }
  }
  for (int k4 = 0; k4 < IN_CH/4; ++k4){
    float w0 = wThh[(4*k4+0)*G4 + g];
    float w1 = wThh[(4*k4+1)*G4 + g];
    float w2 = wThh[(4*k4+2)*G4 + g];
    float w3 = wThh[(4*k4+3)*G4 + g];
#pragma unroll
    for (int r = 0; r < 8; ++r){
      float4 hv = *reinterpret_cast<const float4*>(&hs[r][4*k4]);
      acc[r] += hv.x*w0 + hv.y*w1 + hv.z*w2 + hv.w*w3;
    }
  }
#pragma unroll
  for (int r = 0; r < 8; ++r) gs[r][g] = acc[r];
  __syncthreads();
  for (int t = g; t < 8*IN_CH; t += 512){
    int r = t >> 7, ch = t & 127;
    int idx = (row0+r)*IN_CH + ch;
    float iv = sigmoidf_(gs[r][ch]);
    float fv = sigmoidf_(gs[r][IN_CH + ch]);
    float gv = tanhf(gs[r][2*IN_CH + ch]);
    float ov = sigmoidf_(gs[r][3*IN_CH + ch]);
    float cv = fv*c[idx] + iv*gv;
    float hv = ov*tanhf(cv);
    c[idx] = cv; h[idx] = hv;
    qstar_out[(row0+r)*K1 + ch] = hv;
  }
}

// Single-pass online-softmax weighted readout. 16 lanes per row (8 channels/lane),
// pure-DPP 16-lane reduce, deferred-max rescale. 4 rows per wave per unrolled pair.
__global__ __launch_bounds__(256) void attn_part_kernel(const float* __restrict__ x,
    const float* __restrict__ qstar, const int* __restrict__ segs,
    float* __restrict__ pm, float* __restrict__ pd, float* __restrict__ pr){
  int b = blockIdx.x, p = blockIdx.y;
  int s = segs[b], t = segs[b+1];
  int len = t - s;
  int cs = s + (int)(((long long)len * p) / SPLIT);
  int ce = s + (int)(((long long)len * (p+1)) / SPLIT);
  int tid = threadIdx.x;
  int wave = tid >> 6, lane = tid & 63;
  int grp = (lane >> 4) & 3, l16 = lane & 15;
  int sid = wave*4 + grp;           // 16 streams per block
  const float4 z4 = make_float4(0.f,0.f,0.f,0.f);
  const float4* x4 = reinterpret_cast<const float4*>(x);
  const float4* q4 = reinterpret_cast<const float4*>(&qstar[(size_t)b*K1]);
  float4 qa = q4[l16], qb = q4[16 + l16];   // channels l16*4..+3 and 64+l16*4..+3

  float m = -INFINITY, d = 0.f;
  float4 ra = z4, rb = z4;

  for (int j0 = cs + sid*2; j0 < ce; j0 += 32){
    int j1 = j0 + 1;
    bool ok1 = (j1 < ce);
    const float4* r0 = x4 + (size_t)j0*(IN_CH/4);
    const float4* r1 = x4 + (size_t)j1*(IN_CH/4);
    float4 a0 = r0[l16],        b0 = r0[16 + l16];
    float4 a1 = ok1 ? r1[l16] : z4, b1 = ok1 ? r1[16 + l16] : z4;
    float e0 = dot4_(a0, qa) + dot4_(b0, qb);
    float e1 = dot4_(a1, qa) + dot4_(b1, qb);
    e0 = reduce16_(e0);
    e1 = reduce16_(e1);
    e1 = ok1 ? e1 : -INFINITY;
    float em = fmaxf(e0, e1);
    if (em > m){                       // group-uniform; rarely taken after warmup
      float corr = __expf(m - em);     // m=-inf first time -> corr=0 zeroes state
      d *= corr;
      ra.x *= corr; ra.y *= corr; ra.z *= corr; ra.w *= corr;
      rb.x *= corr; rb.y *= corr; rb.z *= corr; rb.w *= corr;
      m = em;
    }
    float p0 = __expf(e0 - m);
    float p1 = __expf(e1 - m);
    d += p0 + p1;
    ra.x += p0*a0.x + p1*a1.x; ra.y += p0*a0.y + p1*a1.y;
    ra.z += p0*a0.z + p1*a1.z; ra.w += p0*a0.w + p1*a1.w;
    rb.x += p0*b0.x + p1*b1.x; rb.y += p0*b0.y + p1*b1.y;
    rb.z += p0*b0.z + p1*b1.z; rb.w += p0*b0.w + p1*b1.w;
  }
  // merge group pairs: lane^16 (ds_swizzle), then lane^32 (shfl)
  {
    float mo = swz16_(m), dd = swz16_(d);
    float4 rao, rbo;
    rao.x = swz16_(ra.x); rao.y = swz16_(ra.y); rao.z = swz16_(ra.z); rao.w = swz16_(ra.w);
    rbo.x = swz16_(rb.x); rbo.y = swz16_(rb.y); rbo.z = swz16_(rb.z); rbo.w = swz16_(rb.w);
    float mn = fmaxf(m, mo);
    float c1 = (mn == -INFINITY) ? 0.f : __expf(m - mn);
    float c2 = (mn == -INFINITY) ? 0.f : __expf(mo - mn);
    d = d*c1 + dd*c2;
    ra.x = ra.x*c1 + rao.x*c2; ra.y = ra.y*c1 + rao.y*c2;
    ra.z = ra.z*c1 + rao.z*c2; ra.w = ra.w*c1 + rao.w*c2;
    rb.x = rb.x*c1 + rbo.x*c2; rb.y = rb.y*c1 + rbo.y*c2;
    rb.z = rb.z*c1 + rbo.z*c2; rb.w = rb.w*c1 + rbo.w*c2;
    m = mn;
  }
  {
    float mo = __shfl_xor(m, 32), dd = __shfl_xor(d, 32);
    float4 rao, rbo;
    rao.x = __shfl_xor(ra.x, 32); rao.y = __shfl_xor(ra.y, 32);
    rao.z = __shfl_xor(ra.z, 32); rao.w = __shfl_xor(ra.w, 32);
    rbo.x = __shfl_xor(rb.x, 32); rbo.y = __shfl_xor(rb.y, 32);
    rbo.z = __shfl_xor(rb.z, 32); rbo.w = __shfl_xor(rb.w, 32);
    float mn = fmaxf(m, mo);
    float c1 = (mn == -INFINITY) ? 0.f : __expf(m - mn);
    float c2 = (mn == -INFINITY) ? 0.f : __expf(mo - mn);
    d = d*c1 + dd*c2;
    ra.x = ra.x*c1 + rao.x*c2; ra.y = ra.y*c1 + rao.y*c2;
    ra.z = ra.z*c1 + rao.z*c2; ra.w = ra.w*c1 + rao.w*c2;
    rb.x = rb.x*c1 + rbo.x*c2; rb.y = rb.y*c1 + rbo.y*c2;
    rb.z = rb.z*c1 + rbo.z*c2; rb.w = rb.w*c1 + rbo.w*c2;
    m = mn;
  }
  __shared__ float mbuf[4], dbuf[4];
  __shared__ float rbA[4][64], rbB[4][64];
  if (lane < 16){
    *reinterpret_cast<float4*>(&rbA[wave][l16*4]) = ra;
    *reinterpret_cast<float4*>(&rbB[wave][l16*4]) = rb;
    if (l16 == 0){ mbuf[wave] = m; dbuf[wave] = d; }
  }
  __syncthreads();
  int part = b*SPLIT + p;
  if (tid < IN_CH){
    float M = fmaxf(fmaxf(mbuf[0], mbuf[1]), fmaxf(mbuf[2], mbuf[3]));
    float f0 = (M == -INFINITY) ? 0.f : __expf(mbuf[0] - M);
    float f1 = (M == -INFINITY) ? 0.f : __expf(mbuf[1] - M);
    float f2 = (M == -INFINITY) ? 0.f : __expf(mbuf[2] - M);
    float f3 = (M == -INFINITY) ? 0.f : __expf(mbuf[3] - M);
    float v0 = (tid < 64) ? rbA[0][tid] : rbB[0][tid-64];
    float v1 = (tid < 64) ? rbA[1][tid] : rbB[1][tid-64];
    float v2 = (tid < 64) ? rbA[2][tid] : rbB[2][tid-64];
    float v3 = (tid < 64) ? rbA[3][tid] : rbB[3][tid-64];
    pr[(size_t)part*IN_CH + tid] = v0*f0 + v1*f1 + v2*f2 + v3*f3;
    if (tid == 0){
      pd[part] = dbuf[0]*f0 + dbuf[1]*f1 + dbuf[2]*f2 + dbuf[3]*f3;
      pm[part] = M;
    }
  }
}

// Final combine (after last attn): write r-half of q_star
__global__ void attn_combine_kernel(const float* __restrict__ pm, const float* __restrict__ pd,
                                    const float* __restrict__ pr, float* __restrict__ qstar){
  int b = blockIdx.x; int ch = threadIdx.x;  // 128 threads
  float M = -INFINITY;
#pragma unroll
  for (int p = 0; p < SPLIT; ++p) M = fmaxf(M, pm[b*SPLIT + p]);
  float d = 0.f, r = 0.f;
#pragma unroll
  for (int p = 0; p < SPLIT; ++p){
    float mp = pm[b*SPLIT + p];
    float f = (mp == -INFINITY) ? 0.f : __expf(mp - M);
    d += pd[b*SPLIT + p] * f;
    r += pr[(size_t)(b*SPLIT + p)*IN_CH + ch] * f;
  }
  qstar[b*K1 + IN_CH + ch] = (d > 0.f) ? r/d : 0.f;
}

extern "C" void kernel_launch(void* const* d_in, const int* in_sizes, int n_in,
                              void* d_out, int out_size, void* d_ws, size_t ws_size,
                              hipStream_t stream){
  const float* x     = (const float*)d_in[0];
  const float* w_ih  = (const float*)d_in[1];
  const float* w_hh  = (const float*)d_in[2];
  const float* b_ih  = (const float*)d_in[3];
  const float* b_hh  = (const float*)d_in[4];
  const int*   batch = (const int*)d_in[5];
  int N = in_sizes[0] / IN_CH;
  int B = out_size / K1;
  float* out = (float*)d_out;   // q_star lives here

  float* ws    = (float*)d_ws;
  float* h     = ws;                    // B*128
  float* c     = h + (size_t)B*IN_CH;   // B*128
  float* wTih  = c + (size_t)B*IN_CH;   // 256*512
  float* wThh  = wTih + K1*G4;          // 128*512
  int*   segs  = (int*)(wThh + IN_CH*G4);      // B+1
  float* pm    = (float*)(segs + (B + 2));     // B*SPLIT
  float* pd    = pm + (size_t)B*SPLIT;         // B*SPLIT
  float* pr    = pd + (size_t)B*SPLIT;         // B*SPLIT*128

  prologue_kernel<<<517 + (B*IN_CH + 255)/256, 256, 0, stream>>>(
      w_ih, w_hh, wTih, wThh, batch, N, B, segs, b_ih, b_hh, h, c, out);

  attn_part_kernel<<<dim3(B, SPLIT), 256, 0, stream>>>(x, out, segs, pm, pd, pr);
  for (int step = 1; step < 3; ++step){
    lstm_fused_kernel<<<B/8, 512, 0, stream>>>(out, pm, pd, pr, h, c, wTih, wThh, b_ih, b_hh, out);
    attn_part_kernel<<<dim3(B, SPLIT), 256, 0, stream>>>(x, out, segs, pm, pd, pr);
  }
  attn_combine_kernel<<<B, IN_CH, 0, stream>>>(pm, pd, pr, out);
}